// Round 6
// baseline (593.730 us; speedup 1.0000x reference)
//
#include <hip/hip_runtime.h>

// Problem constants (B=64, T=512, I=256, H=512)
#define BATCH 64
#define TSTEPS 512
#define IDIM 256
#define HDIM 512
#define MROWS (BATCH * TSTEPS)   // 32768

typedef __attribute__((address_space(1))) const void gvoid;
typedef __attribute__((address_space(3))) void lvoid;

__device__ __forceinline__ void gl2lds16(const void* g, void* l) {
    // async global->LDS, 16B per lane; LDS dest = wave-uniform base + lane*16
    __builtin_amdgcn_global_load_lds((gvoid*)g, (lvoid*)l, 16, 0, 0);
}

// ---------------------------------------------------------------------------
// K0: extract center taps: W1T[i][h] = conv1_w[h][i][1] ([k][n] layout);
//                          W2T[h][j] = conv2_w[j][h][1] ([k][n] layout)
// ---------------------------------------------------------------------------
__global__ void extract_weights(const float* __restrict__ c1w,
                                const float* __restrict__ c2w,
                                float* __restrict__ W1T,
                                float* __restrict__ W2T) {
    int tid = blockIdx.x * 256 + threadIdx.x;
    if (tid < IDIM * HDIM) {
        int i = tid >> 9;          // / 512
        int h = tid & 511;
        W1T[tid] = c1w[(h * IDIM + i) * 3 + 1];
    }
    if (tid < HDIM * HDIM) {
        int h = tid >> 9;
        int j = tid & 511;
        W2T[tid] = c2w[(j * HDIM + h) * 3 + 1];
    }
}

// ---------------------------------------------------------------------------
// fp32 GEMM: C[m][n] = (sum_k A[m][k]*BT[k][n]) [+ bias[n]]
// NUMERICS CONTRACT: each output is ONE sequential fmaf chain, k ascending,
// fp32 — bitwise identical to rounds 1/4/5 (absmax 0.0). MFMA / split-K /
// tree reductions flip spikes (rounds 2/3 evidence).
//
// Round-5 lesson: pipe-ratio alone isn't the bottleneck — latency exposure
// at low occupancy is. This kernel buys latency-hiding with ILP instead of
// TLP: 16x16 thread tile -> 256 independent FMAs (512 SIMD-cyc) per k-step
// per wave vs 8 ds_read_b128 (96 LDS-cyc) -> VALU-bound (per-CU LDS 384 <
// VALU 512), and k+1 fragment reads prefetch under k's FMA block.
// 128 threads (2 waves), BM=128 BN=256 -> 512 blocks = 2 independent
// blocks/CU (one block computes while the other sits at its barrier).
// launch_bounds(128,1): ~340 VGPRs needed (acc 256 + frags + addr), max 512.
// Bank behavior: A-scatter 2-way (free); A-reads = round-5 pattern (measured
// 0 conflicts); B-reads 4-way same-address broadcast x 2-way distinct (free).
// ---------------------------------------------------------------------------
#define BM 128
#define BN 256
#define BK 16

__global__ __launch_bounds__(128, 1) void gemm_f32(const float* __restrict__ A,
                                                   const float* __restrict__ BT,
                                                   const float* __restrict__ bias,
                                                   float* __restrict__ C,
                                                   int K, int addBias) {
    __shared__ __align__(16) float As[BK * BM];   // [k][m]   8 KB
    __shared__ __align__(16) float Bs[BK * BN];   // [k][n]  16 KB

    const int N = HDIM;
    int tid  = threadIdx.x;          // 0..127
    int row0 = blockIdx.x * BM;
    int col0 = blockIdx.y * BN;
    int hg = tid >> 4;               // m-group 0..7   (rows hg*4 + s*32 + i)
    int gg = tid & 15;               // n-group 0..15  (cols gg*4 + t*64 + j)

    float acc[16][16];
#pragma unroll
    for (int i = 0; i < 16; i++)
#pragma unroll
        for (int j = 0; j < 16; j++) acc[i][j] = 0.0f;

    // A staging: thread tid owns global row (row0+tid); loads 16 floats/tile,
    // scatters transposed into As[k][tid] (banks tid%32 -> 2-way, free).
    const float* ap = A + (size_t)(row0 + tid) * K;

    // B staging via global_load_lds: inst q covers k-rows 2q..2q+1;
    // thread t -> k-row (t>>6), bytes (t&63)*16. LDS dest = Bs + tid*16
    // (+ q*2048), matching the wave-uniform-base + lane*16 contract.
    const char* bp = (const char*)(BT + (size_t)(tid >> 6) * N + col0) + (tid & 63) * 16;
    char* bld = (char*)Bs + tid * 16;
    const size_t bRow2 = (size_t)2 * N * sizeof(float);   // +2 k-rows

    for (int k0 = 0; k0 < K; k0 += BK) {
#pragma unroll
        for (int q = 0; q < 8; q++)
            gl2lds16(bp + q * bRow2, bld + q * 2048);
        float4 a0 = *(const float4*)(ap);
        float4 a1 = *(const float4*)(ap + 4);
        float4 a2 = *(const float4*)(ap + 8);
        float4 a3 = *(const float4*)(ap + 12);
        ap += BK;
        bp += (size_t)BK * N * sizeof(float);
        As[ 0 * BM + tid] = a0.x;  As[ 1 * BM + tid] = a0.y;
        As[ 2 * BM + tid] = a0.z;  As[ 3 * BM + tid] = a0.w;
        As[ 4 * BM + tid] = a1.x;  As[ 5 * BM + tid] = a1.y;
        As[ 6 * BM + tid] = a1.z;  As[ 7 * BM + tid] = a1.w;
        As[ 8 * BM + tid] = a2.x;  As[ 9 * BM + tid] = a2.y;
        As[10 * BM + tid] = a2.z;  As[11 * BM + tid] = a2.w;
        As[12 * BM + tid] = a3.x;  As[13 * BM + tid] = a3.y;
        As[14 * BM + tid] = a3.z;  As[15 * BM + tid] = a3.w;
        __syncthreads();

#pragma unroll
        for (int k = 0; k < BK; k++) {
            // A: rows hg*4 + s*32 (+i) — round-5 pattern, 0 conflicts measured
            float4 av[4];
#pragma unroll
            for (int s = 0; s < 4; s++)
                av[s] = *(const float4*)&As[k * BM + hg * 4 + s * 32];
            // B: cols gg*4 + t*64 (+j) — 4-way broadcast x 2-way alias (free)
            float4 bv[4];
#pragma unroll
            for (int t = 0; t < 4; t++)
                bv[t] = *(const float4*)&Bs[k * BN + gg * 4 + t * 64];
            const float* a16 = (const float*)av;   // 16 row values
            const float* b16 = (const float*)bv;   // 16 col values
#pragma unroll
            for (int i = 0; i < 16; i++)
#pragma unroll
                for (int j = 0; j < 16; j++)
                    acc[i][j] = fmaf(a16[i], b16[j], acc[i][j]);
        }
        __syncthreads();
    }

    // Epilogue: rows hg*4+s*32+i, cols gg*4+t*64+j ; float4 stores
    float bb[16];
#pragma unroll
    for (int t = 0; t < 4; t++)
#pragma unroll
        for (int j = 0; j < 4; j++)
            bb[t * 4 + j] = addBias ? bias[col0 + gg * 4 + t * 64 + j] : 0.0f;
#pragma unroll
    for (int s = 0; s < 4; s++)
#pragma unroll
        for (int i = 0; i < 4; i++) {
            int row = row0 + hg * 4 + s * 32 + i;
            float* cp = &C[(size_t)row * N + col0 + gg * 4];
#pragma unroll
            for (int t = 0; t < 4; t++) {
                float4 v;
                v.x = acc[s * 4 + i][t * 4 + 0] + bb[t * 4 + 0];
                v.y = acc[s * 4 + i][t * 4 + 1] + bb[t * 4 + 1];
                v.z = acc[s * 4 + i][t * 4 + 2] + bb[t * 4 + 2];
                v.w = acc[s * 4 + i][t * 4 + 3] + bb[t * 4 + 3];
                *(float4*)(cp + t * 64) = v;
            }
        }
}

// ---------------------------------------------------------------------------
// K2: per-(b,h) LIF scan. 64-thread blocks (512 blocks -> 2 waves/CU), 16-deep
// ILP batching. Arithmetic identical to round 1 (sequential per element).
// ---------------------------------------------------------------------------
__global__ void lif_scan1(const float* __restrict__ z1,
                          float* __restrict__ s1,
                          const float* __restrict__ th_p) {
    int gtid = blockIdx.x * blockDim.x + threadIdx.x;   // 0..32767
    int b = gtid >> 9;
    int h = gtid & 511;
    float th = *th_p;
    const float* zp = z1 + (size_t)b * TSTEPS * HDIM + h;
    float* sp = s1 + (size_t)b * TSTEPS * HDIM + h;
    float m = 0.0f;
    for (int t0 = 0; t0 < TSTEPS; t0 += 16) {
        float zz[16];
#pragma unroll
        for (int i = 0; i < 16; i++) zz[i] = zp[(size_t)(t0 + i) * HDIM];
        float ss[16];
#pragma unroll
        for (int i = 0; i < 16; i++) {
            m += zz[i];
            float thr = m / th - 1.0f;
            ss[i] = (thr >= 0.0f) ? 1.0f : 0.0f;
            if (thr > 0.0f) m -= th;   // exact: m - th*1.0
        }
#pragma unroll
        for (int i = 0; i < 16; i++) sp[(size_t)(t0 + i) * HDIM] = ss[i];
    }
}

// ---------------------------------------------------------------------------
// K4: per-(b,j) scan: m2 = (m2 + raw[t]) + bias, spike/reset -> out
// ---------------------------------------------------------------------------
__global__ void lif_scan2(const float* __restrict__ raw,
                          const float* __restrict__ b2,
                          const float* __restrict__ th_p,
                          float* __restrict__ out) {
    int gtid = blockIdx.x * blockDim.x + threadIdx.x;   // 0..32767
    int b = gtid >> 9;
    int j = gtid & 511;
    float th = *th_p;
    float bias = b2[j];
    const float* rp = raw + (size_t)b * TSTEPS * HDIM + j;
    float* op = out + (size_t)b * TSTEPS * HDIM + j;
    float m = 0.0f;
    for (int t0 = 0; t0 < TSTEPS; t0 += 16) {
        float rr[16];
#pragma unroll
        for (int i = 0; i < 16; i++) rr[i] = rp[(size_t)(t0 + i) * HDIM];
        float ss[16];
#pragma unroll
        for (int i = 0; i < 16; i++) {
            m = (m + rr[i]) + bias;
            float thr = m / th - 1.0f;
            ss[i] = (thr >= 0.0f) ? 1.0f : 0.0f;
            if (thr > 0.0f) m -= th;
        }
#pragma unroll
        for (int i = 0; i < 16; i++) op[(size_t)(t0 + i) * HDIM] = ss[i];
    }
}

// ---------------------------------------------------------------------------
extern "C" void kernel_launch(void* const* d_in, const int* in_sizes, int n_in,
                              void* d_out, int out_size, void* d_ws, size_t ws_size,
                              hipStream_t stream) {
    const float* x    = (const float*)d_in[0];   // (64, 512, 256)
    const float* c1w  = (const float*)d_in[1];   // (512, 256, 3)
    const float* c1b  = (const float*)d_in[2];   // (512,)
    const float* c2w  = (const float*)d_in[3];   // (512, 512, 3)
    const float* c2b  = (const float*)d_in[4];   // (512,)
    const float* th1  = (const float*)d_in[5];   // scalar
    const float* th2  = (const float*)d_in[6];   // scalar
    float* out = (float*)d_out;                  // (64, 512, 512)

    // Workspace layout (floats):
    //   W1T : 131072   (512 KB)   [k=i][n=h]
    //   W2T : 262144   (1 MB)     [k=h][n=j]
    //   bufA: 16777216 (64 MB)    z1, later m2raw
    //   bufS: 16777216 (64 MB)    s1
    float* W1T  = (float*)d_ws;
    float* W2T  = W1T + IDIM * HDIM;
    float* bufA = W2T + HDIM * HDIM;
    float* bufS = bufA + (size_t)MROWS * HDIM;

    // K0: weight extraction
    extract_weights<<<(HDIM * HDIM + 255) / 256, 256, 0, stream>>>(c1w, c2w, W1T, W2T);

    // K1: z1 = x @ W1T + b1   (M=32768, K=256, N=512) -> bufA
    {
        dim3 grid(MROWS / BM, HDIM / BN);
        gemm_f32<<<grid, 128, 0, stream>>>(x, W1T, c1b, bufA, IDIM, 1);
    }

    // K2: s1 scan -> bufS
    lif_scan1<<<MROWS / 64, 64, 0, stream>>>(bufA, bufS, th1);

    // K3: m2raw = s1 @ W2T   (M=32768, K=512, N=512) -> bufA
    {
        dim3 grid(MROWS / BM, HDIM / BN);
        gemm_f32<<<grid, 128, 0, stream>>>(bufS, W2T, (const float*)nullptr, bufA, HDIM, 0);
    }

    // K4: s2 scan -> out
    lif_scan2<<<MROWS / 64, 64, 0, stream>>>(bufA, c2b, th2, out);
}

// Round 7
// 432.854 us; speedup vs baseline: 1.3717x; 1.3717x over previous
//
#include <hip/hip_runtime.h>

// Problem constants (B=64, T=512, I=256, H=512)
#define BATCH 64
#define TSTEPS 512
#define IDIM 256
#define HDIM 512
#define MROWS (BATCH * TSTEPS)   // 32768

typedef __attribute__((address_space(1))) const void gvoid;
typedef __attribute__((address_space(3))) void lvoid;

__device__ __forceinline__ void gl2lds16(const void* g, void* l) {
    // async global->LDS, 16B per lane; LDS dest = wave-uniform base + lane*16
    __builtin_amdgcn_global_load_lds((gvoid*)g, (lvoid*)l, 16, 0, 0);
}

// ---------------------------------------------------------------------------
// K0: extract center taps: W1T[i][h] = conv1_w[h][i][1] ([k][n] layout);
//                          W2T[h][j] = conv2_w[j][h][1] ([k][n] layout)
// ---------------------------------------------------------------------------
__global__ void extract_weights(const float* __restrict__ c1w,
                                const float* __restrict__ c2w,
                                float* __restrict__ W1T,
                                float* __restrict__ W2T) {
    int tid = blockIdx.x * 256 + threadIdx.x;
    if (tid < IDIM * HDIM) {
        int i = tid >> 9;          // / 512
        int h = tid & 511;
        W1T[tid] = c1w[(h * IDIM + i) * 3 + 1];
    }
    if (tid < HDIM * HDIM) {
        int h = tid >> 9;
        int j = tid & 511;
        W2T[tid] = c2w[(j * HDIM + h) * 3 + 1];
    }
}

// ---------------------------------------------------------------------------
// fp32 GEMM: C[m][n] = (sum_k A[m][k]*BT[k][n]) [+ bias[n]]
// NUMERICS CONTRACT: each output is ONE sequential fmaf chain, k ascending,
// fp32 — bitwise identical to rounds 1/4/5 (absmax 0.0). MFMA / split-K /
// tree reductions flip spikes (rounds 2/3 evidence).
//
// Model (fits R4/R5/R6 counters): per CU per k-step, VALU demand =
// waves*tm*tn/2 cyc spread over 4 SIMDs; LDS pipe demand = waves*(tm+tn)/4
// instrs * ~8-12 cyc, single pipe. R6 lesson: acc >= 256 regs breaks the
// allocator (VGPR 168 + scratch shuffling, occupancy 11%). This kernel:
// 16x8 tile (acc=128, R5-proven), 256 threads, BM=256 BN=128,
// launch_bounds(256,2) -> 2 blocks/CU = 8 waves/CU; per k-step VALU 512
// cyc/CU vs LDS ~400 -> VALU-bound with barrier overlap across blocks.
// A-reads 16-way broadcast (4x16B unique), B-reads 4-way broadcast — cheap.
// ---------------------------------------------------------------------------
#define BM 256
#define BN 128
#define BK 16

__global__ __launch_bounds__(256, 2) void gemm_f32(const float* __restrict__ A,
                                                   const float* __restrict__ BT,
                                                   const float* __restrict__ bias,
                                                   float* __restrict__ C,
                                                   int K, int addBias) {
    __shared__ __align__(16) float As[BK * BM];   // [k][m]  16 KB
    __shared__ __align__(16) float Bs[BK * BN];   // [k][n]   8 KB

    const int N = HDIM;
    int tid  = threadIdx.x;          // 0..255
    int row0 = blockIdx.x * BM;
    int col0 = blockIdx.y * BN;
    int hg = tid >> 4;               // m-group 0..15  (rows hg*4 + s*64 + i)
    int gg = tid & 15;               // n-group 0..15  (cols gg*4 + t*64 + j)

    float acc[16][8];
#pragma unroll
    for (int i = 0; i < 16; i++)
#pragma unroll
        for (int j = 0; j < 8; j++) acc[i][j] = 0.0f;

    // A staging: thread tid owns global row (row0+tid); loads 16 floats/tile,
    // scatters transposed into As[k][tid] (banks tid%32 -> 2-way, free).
    const float* ap = A + (size_t)(row0 + tid) * K;

    // B staging via global_load_lds: thread t covers 16B chunk at float
    // offset t*4: k-row t>>5, cols (t&31)*4. Second instr: +8 k-rows.
    const char* bp = (const char*)(BT + (size_t)(tid >> 5) * N + col0) + (tid & 31) * 16;
    char* bld = (char*)Bs + tid * 16;
    const size_t bRow8 = (size_t)8 * N * sizeof(float);

    for (int k0 = 0; k0 < K; k0 += BK) {
        gl2lds16(bp,         bld);
        gl2lds16(bp + bRow8, bld + 4096);
        float4 a0 = *(const float4*)(ap);
        float4 a1 = *(const float4*)(ap + 4);
        float4 a2 = *(const float4*)(ap + 8);
        float4 a3 = *(const float4*)(ap + 12);
        ap += BK;
        bp += (size_t)BK * N * sizeof(float);
        As[ 0 * BM + tid] = a0.x;  As[ 1 * BM + tid] = a0.y;
        As[ 2 * BM + tid] = a0.z;  As[ 3 * BM + tid] = a0.w;
        As[ 4 * BM + tid] = a1.x;  As[ 5 * BM + tid] = a1.y;
        As[ 6 * BM + tid] = a1.z;  As[ 7 * BM + tid] = a1.w;
        As[ 8 * BM + tid] = a2.x;  As[ 9 * BM + tid] = a2.y;
        As[10 * BM + tid] = a2.z;  As[11 * BM + tid] = a2.w;
        As[12 * BM + tid] = a3.x;  As[13 * BM + tid] = a3.y;
        As[14 * BM + tid] = a3.z;  As[15 * BM + tid] = a3.w;
        __syncthreads();

#pragma unroll
        for (int k = 0; k < BK; k++) {
            // A: rows hg*4 + s*64 — per instr 4 distinct 16B chunks,
            //    16-way same-address broadcast (free), banks disjoint.
            float4 av[4];
#pragma unroll
            for (int s = 0; s < 4; s++)
                av[s] = *(const float4*)&As[k * BM + hg * 4 + s * 64];
            // B: cols gg*4 + t*64 — 16 distinct chunks, 4-way broadcast.
            float4 bv[2];
#pragma unroll
            for (int t = 0; t < 2; t++)
                bv[t] = *(const float4*)&Bs[k * BN + gg * 4 + t * 64];
            const float* a16 = (const float*)av;   // 16 row values
            const float* b8  = (const float*)bv;   // 8 col values
#pragma unroll
            for (int i = 0; i < 16; i++)
#pragma unroll
                for (int j = 0; j < 8; j++)
                    acc[i][j] = fmaf(a16[i], b8[j], acc[i][j]);
        }
        __syncthreads();
    }

    // Epilogue: rows hg*4+s*64+i, cols gg*4+t*64+j ; float4 stores
    float bb[8];
#pragma unroll
    for (int t = 0; t < 2; t++)
#pragma unroll
        for (int j = 0; j < 4; j++)
            bb[t * 4 + j] = addBias ? bias[col0 + gg * 4 + t * 64 + j] : 0.0f;
#pragma unroll
    for (int s = 0; s < 4; s++)
#pragma unroll
        for (int i = 0; i < 4; i++) {
            int row = row0 + hg * 4 + s * 64 + i;
            float* cp = &C[(size_t)row * N + col0 + gg * 4];
#pragma unroll
            for (int t = 0; t < 2; t++) {
                float4 v;
                v.x = acc[s * 4 + i][t * 4 + 0] + bb[t * 4 + 0];
                v.y = acc[s * 4 + i][t * 4 + 1] + bb[t * 4 + 1];
                v.z = acc[s * 4 + i][t * 4 + 2] + bb[t * 4 + 2];
                v.w = acc[s * 4 + i][t * 4 + 3] + bb[t * 4 + 3];
                *(float4*)(cp + t * 64) = v;
            }
        }
}

// ---------------------------------------------------------------------------
// K2: per-(b,h) LIF scan with PING-PONG REGISTER PREFETCH: load batch i+1
// while computing batch i -> per-batch cost max(latency, compute) not sum.
// Arithmetic identical to round 1 (sequential per element).
// ---------------------------------------------------------------------------
__global__ void lif_scan1(const float* __restrict__ z1,
                          float* __restrict__ s1,
                          const float* __restrict__ th_p) {
    int gtid = blockIdx.x * blockDim.x + threadIdx.x;   // 0..32767
    int b = gtid >> 9;
    int h = gtid & 511;
    float th = *th_p;
    const float* zp = z1 + (size_t)b * TSTEPS * HDIM + h;
    float* sp = s1 + (size_t)b * TSTEPS * HDIM + h;
    float m = 0.0f;
    float bufA[16], bufB[16];
#pragma unroll
    for (int i = 0; i < 16; i++) bufA[i] = zp[(size_t)i * HDIM];
    for (int t0 = 0; t0 < TSTEPS; t0 += 32) {
        // prefetch t0+16 while processing t0
#pragma unroll
        for (int i = 0; i < 16; i++) bufB[i] = zp[(size_t)(t0 + 16 + i) * HDIM];
        {
            float ss[16];
#pragma unroll
            for (int i = 0; i < 16; i++) {
                m += bufA[i];
                float thr = m / th - 1.0f;
                ss[i] = (thr >= 0.0f) ? 1.0f : 0.0f;
                if (thr > 0.0f) m -= th;
            }
#pragma unroll
            for (int i = 0; i < 16; i++) sp[(size_t)(t0 + i) * HDIM] = ss[i];
        }
        // prefetch t0+32 while processing t0+16
        if (t0 + 32 < TSTEPS) {
#pragma unroll
            for (int i = 0; i < 16; i++) bufA[i] = zp[(size_t)(t0 + 32 + i) * HDIM];
        }
        {
            float ss[16];
#pragma unroll
            for (int i = 0; i < 16; i++) {
                m += bufB[i];
                float thr = m / th - 1.0f;
                ss[i] = (thr >= 0.0f) ? 1.0f : 0.0f;
                if (thr > 0.0f) m -= th;
            }
#pragma unroll
            for (int i = 0; i < 16; i++) sp[(size_t)(t0 + 16 + i) * HDIM] = ss[i];
        }
    }
}

// ---------------------------------------------------------------------------
// K4: per-(b,j) scan: m2 = (m2 + raw[t]) + bias, spike/reset -> out.
// Same ping-pong prefetch structure.
// ---------------------------------------------------------------------------
__global__ void lif_scan2(const float* __restrict__ raw,
                          const float* __restrict__ b2,
                          const float* __restrict__ th_p,
                          float* __restrict__ out) {
    int gtid = blockIdx.x * blockDim.x + threadIdx.x;   // 0..32767
    int b = gtid >> 9;
    int j = gtid & 511;
    float th = *th_p;
    float bias = b2[j];
    const float* rp = raw + (size_t)b * TSTEPS * HDIM + j;
    float* op = out + (size_t)b * TSTEPS * HDIM + j;
    float m = 0.0f;
    float bufA[16], bufB[16];
#pragma unroll
    for (int i = 0; i < 16; i++) bufA[i] = rp[(size_t)i * HDIM];
    for (int t0 = 0; t0 < TSTEPS; t0 += 32) {
#pragma unroll
        for (int i = 0; i < 16; i++) bufB[i] = rp[(size_t)(t0 + 16 + i) * HDIM];
        {
            float ss[16];
#pragma unroll
            for (int i = 0; i < 16; i++) {
                m = (m + bufA[i]) + bias;
                float thr = m / th - 1.0f;
                ss[i] = (thr >= 0.0f) ? 1.0f : 0.0f;
                if (thr > 0.0f) m -= th;
            }
#pragma unroll
            for (int i = 0; i < 16; i++) op[(size_t)(t0 + i) * HDIM] = ss[i];
        }
        if (t0 + 32 < TSTEPS) {
#pragma unroll
            for (int i = 0; i < 16; i++) bufA[i] = rp[(size_t)(t0 + 32 + i) * HDIM];
        }
        {
            float ss[16];
#pragma unroll
            for (int i = 0; i < 16; i++) {
                m = (m + bufB[i]) + bias;
                float thr = m / th - 1.0f;
                ss[i] = (thr >= 0.0f) ? 1.0f : 0.0f;
                if (thr > 0.0f) m -= th;
            }
#pragma unroll
            for (int i = 0; i < 16; i++) op[(size_t)(t0 + 16 + i) * HDIM] = ss[i];
        }
    }
}

// ---------------------------------------------------------------------------
extern "C" void kernel_launch(void* const* d_in, const int* in_sizes, int n_in,
                              void* d_out, int out_size, void* d_ws, size_t ws_size,
                              hipStream_t stream) {
    const float* x    = (const float*)d_in[0];   // (64, 512, 256)
    const float* c1w  = (const float*)d_in[1];   // (512, 256, 3)
    const float* c1b  = (const float*)d_in[2];   // (512,)
    const float* c2w  = (const float*)d_in[3];   // (512, 512, 3)
    const float* c2b  = (const float*)d_in[4];   // (512,)
    const float* th1  = (const float*)d_in[5];   // scalar
    const float* th2  = (const float*)d_in[6];   // scalar
    float* out = (float*)d_out;                  // (64, 512, 512)

    // Workspace layout (floats):
    //   W1T : 131072   (512 KB)   [k=i][n=h]
    //   W2T : 262144   (1 MB)     [k=h][n=j]
    //   bufA: 16777216 (64 MB)    z1, later m2raw
    //   bufS: 16777216 (64 MB)    s1
    float* W1T  = (float*)d_ws;
    float* W2T  = W1T + IDIM * HDIM;
    float* bufA = W2T + HDIM * HDIM;
    float* bufS = bufA + (size_t)MROWS * HDIM;

    // K0: weight extraction
    extract_weights<<<(HDIM * HDIM + 255) / 256, 256, 0, stream>>>(c1w, c2w, W1T, W2T);

    // K1: z1 = x @ W1T + b1   (M=32768, K=256, N=512) -> bufA
    {
        dim3 grid(MROWS / BM, HDIM / BN);
        gemm_f32<<<grid, 256, 0, stream>>>(x, W1T, c1b, bufA, IDIM, 1);
    }

    // K2: s1 scan -> bufS
    lif_scan1<<<MROWS / 64, 64, 0, stream>>>(bufA, bufS, th1);

    // K3: m2raw = s1 @ W2T   (M=32768, K=512, N=512) -> bufA
    {
        dim3 grid(MROWS / BM, HDIM / BN);
        gemm_f32<<<grid, 256, 0, stream>>>(bufS, W2T, (const float*)nullptr, bufA, HDIM, 0);
    }

    // K4: s2 scan -> out
    lif_scan2<<<MROWS / 64, 64, 0, stream>>>(bufA, c2b, th2, out);
}